// Round 9
// baseline (517.269 us; speedup 1.0000x reference)
//
#include <hip/hip_runtime.h>
#include <math.h>

#define NPG  100
#define NGR  2048
#define EPG  800
#define HID  64
#define LATD 193
#define KTOP 30
#define NTHR 768     // 12 waves/WG; 2 WGs/CU = 6 waves/SIMD
#define NWV  12
#define ROWS 9       // ceil(100/12)
#define MAXD 32

// ---------------- LDS layout (byte offsets), 64912 B ------------------------
// Residency model CONFIRMED: VGPR<=42 via launch_bounds(768,6) -> 2 WGs/CU
// (occupancy ~67%). r8 cut the spill 510->240 MB via quartet-scalar weights;
// the REMAINING spill is scheduler-transient: fully-unrolled row loops let the
// compiler interleave 5-9 independent chains (esp. 9 inlined ftanh64, ~12 f64
// temps each). This round caps interleaving: 3-row matmul batches, 5+4
// dot_accum split, sched_barrier(0) fences in agg/tanh. All bit-identical.
#define OFF_H64    0       // double[101][64] = 51712 (row 100 = zero sentinel)
#define OFF_ADJ    51712   // ushort[100*32] = 6400 -> 58112 (BYTE offsets u*512; bits0-2 of row[0] = group count)
#define OFF_Y1ALL  58112   // float[100*16] = 6400 -> 64512
#define OFF_DINV   64512   // float[100] = 400 -> 64912 (f64 rsqrt rounded once)
#define SMEM_SZ    64912
// pre-phase-A overlays inside y1all (dead after pad/sort; y1all zeroed later):
#define OFF_ZL     OFF_Y1ALL           // int[100]
#define OFF_CNT    (OFF_Y1ALL + 400)   // int[100]
// tail overlays inside dead h64 region:
#define OFF_Y1P    0       // 960
#define OFF_Y2F    960     // 960+1408 -> 2368
#define OFF_PART   2368    // 6*128*4 = 3072 -> 5440 (4096 reserved)
#define OFF_O128   6464    // 512 -> 6976
#define OFF_Y1     6976    // 16*30*4 = 1920 -> 8896
#define OFF_S4     8896    // double[101] = 808 -> 9704 (written AFTER h64 dead, lane-packed)
#define OFF_KEY64  9704    // double[100] = 800 -> 10504
#define OFF_SEL    10504   // int[32] = 128 -> 10632

// Branch-free f64 tanh (abs err ~1e-13). Divide replaced by float-seeded
// reciprocal + 2 Newton steps (rel err ~1e-28 -> <=1 ulp).
__device__ __forceinline__ double ftanh64(double x) {
    const double y  = fmin(fabs(x) * 2.0, 44.0);
    const double nf = rint(y * 1.4426950408889634074);
    double r = fma(-nf, 6.93147180369123816490e-01, y);
    r = fma(-nf, 1.90821492927058770002e-10, r);
    double p = 2.7557319223985888e-07;
    p = fma(p, r, 2.7557319223985893e-06);
    p = fma(p, r, 2.4801587301587302e-05);
    p = fma(p, r, 1.9841269841269841e-04);
    p = fma(p, r, 1.3888888888888889e-03);
    p = fma(p, r, 8.3333333333333332e-03);
    p = fma(p, r, 4.1666666666666664e-02);
    p = fma(p, r, 1.6666666666666666e-01);
    p = fma(p, r, 0.5);
    p = fma(p, r, 1.0);
    p = fma(p, r, 1.0);
    const double e = p * __longlong_as_double((long long)(1023 + (int)nf) << 52);
    const double d = e + 1.0;
    double rc = (double)(1.0f / (float)d);        // f32 seed (~1.2e-7 rel)
    rc = fma(fma(-d, rc, 1.0), rc, rc);           // Newton 1 -> ~1.4e-14
    rc = fma(fma(-d, rc, 1.0), rc, rc);           // Newton 2 -> exact-ish
    const double t = fma(-2.0, rc, 1.0);
    return copysign(t, x);
}

// Matmul row-batch: rows I0..I0+NI-1 of h@W, written back pre-scaled by dinv.
// QUARTET groups (16 x 4 W-columns) as 4 SCALAR floats (no register arrays
// under partial unroll -- rule #20). NI=3: acc 6 regs, <=6 hoistable double2.
// Each row's summation tree unchanged -> bit-identical to r8.
template<int I0, int NI>
__device__ __forceinline__ void gcn_mm(
    double* __restrict__ h, const float* __restrict__ dinv,
    const float* __restrict__ W, int lane, int wv)
{
    double acc[NI];
#pragma unroll
    for (int i = 0; i < NI; ++i) acc[i] = 0.;

#pragma unroll 1   // one quartet of scalar weights live at a time
    for (int grp = 0; grp < 16; ++grp) {
        const float* wp = &W[(grp*4)*HID + lane];
        const float wfa = wp[0];
        const float wfb = wp[HID];
        const float wfc = wp[2*HID];
        const float wfd = wp[3*HID];
#pragma unroll
        for (int i = 0; i < NI; ++i) {
            const int n = wv + NWV*(I0 + i);
            if (n < NPG) {
                const double2* r2 = (const double2*)&h[n*HID + grp*4];
                const double2 x01 = r2[0], x23 = r2[1];
                const double a0 = x01.x * (double)wfa;
                const double a1 = x01.y * (double)wfb;
                const double a2 = x23.x * (double)wfc;
                const double a3 = x23.y * (double)wfd;
                acc[i] += (a0+a1)+(a2+a3);
            }
        }
    }
#pragma unroll
    for (int i = 0; i < NI; ++i) {
        const int n = wv + NWV*(I0 + i);
        if (n < NPG) h[n*HID + lane] = acc[i] * (double)dinv[n];   // pre-scaled
    }
}

// One adjacency-gather row: returns agg value for row n (pre-barrier state).
__device__ __forceinline__ double agg_row(
    const double* __restrict__ h, const char* __restrict__ hb,
    const unsigned short* __restrict__ adj, const float* __restrict__ dinv,
    double bj, int n, int lane)
{
    const uint4* arow = (const uint4*)&adj[n*MAXD];
    const uint4 q0 = arow[0];
    const int gq = q0.x & 7;          // encoded group count (0..4)
    double a0, a1;
    a0  = *(const double*)(hb + (q0.x & 0xFE00));
    a1  = *(const double*)(hb + (q0.x >> 16));
    a0 += *(const double*)(hb + (q0.y & 0xFE00));
    a1 += *(const double*)(hb + (q0.y >> 16));
    a0 += *(const double*)(hb + (q0.z & 0xFE00));
    a1 += *(const double*)(hb + (q0.z >> 16));
    a0 += *(const double*)(hb + (q0.w & 0xFE00));
    a1 += *(const double*)(hb + (q0.w >> 16));
#pragma unroll 1   // serial q-loop (uint4 qq: vector reg, no array -> safe)
    for (int q = 1; q < gq; ++q) {
        const uint4 qq = arow[q];
        a0 += *(const double*)(hb + (qq.x & 0xFE00));
        a1 += *(const double*)(hb + (qq.x >> 16));
        a0 += *(const double*)(hb + (qq.y & 0xFE00));
        a1 += *(const double*)(hb + (qq.y >> 16));
        a0 += *(const double*)(hb + (qq.z & 0xFE00));
        a1 += *(const double*)(hb + (qq.z >> 16));
        a0 += *(const double*)(hb + (qq.w & 0xFE00));
        a1 += *(const double*)(hb + (qq.w >> 16));
    }
    return fma((a0+a1) + h[n*HID+lane], (double)dinv[n], bj);
}

// f64 in-place GCN layer. Matmul: three 3-row batches. Aggregation: two
// fully-unrolled halves with a sched_barrier(0) fence between them (caps the
// compiler's cross-row chain interleave -- the r8 residual-spill source);
// tanh write-back fenced per row for the same reason. Sentinel terms are
// exact +0.0 -> sums bit-identical regardless of decomposition.
__device__ __forceinline__ void gcnA(
    double* __restrict__ h, const float* __restrict__ dinv,
    const unsigned short* __restrict__ adj,
    const float* __restrict__ W, const float* __restrict__ b, int lane, int wv)
{
    gcn_mm<0, 3>(h, dinv, W, lane, wv);
    gcn_mm<3, 3>(h, dinv, W, lane, wv);
    gcn_mm<6, 3>(h, dinv, W, lane, wv);
    __syncthreads();

    const double bj = (double)b[lane];
    const char* hb = (const char*)h + lane*8;
    double agg[ROWS];
#pragma unroll
    for (int i = 0; i < 5; ++i) {
        const int n = wv + NWV*i;
        if (n < NPG) agg[i] = agg_row(h, hb, adj, dinv, bj, n, lane);
    }
    __builtin_amdgcn_sched_barrier(0);   // fence: no chain interleave across halves
#pragma unroll
    for (int i = 5; i < ROWS; ++i) {
        const int n = wv + NWV*i;
        if (n < NPG) agg[i] = agg_row(h, hb, adj, dinv, bj, n, lane);
    }
    __syncthreads();
#pragma unroll
    for (int i = 0; i < ROWS; ++i) {
        const int n = wv + NWV*i;
        if (n < NPG) h[n*HID + lane] = ftanh64(agg[i]);
        __builtin_amdgcn_sched_barrier(0);   // one tanh chain at a time (~12 f64 temps)
    }
    // no trailing barrier: post-agg ops touch only own rows until next matmul barrier
}

// conv1 partial-dot row batch: rows I0..I0+NI-1, quartet-outer with 4 SCALAR
// weights + persistent s[NI] (static indices -> registers). Per-row k-order
// is 0..15 ascending exactly as r8 -> f32 accumulation BIT-IDENTICAL.
template<int I0, int NI>
__device__ __forceinline__ void dot_part(
    const double* __restrict__ h, const float* __restrict__ wp,
    float* __restrict__ y1all, int lane, int wv, int ch, int j)
{
    float s[NI];
#pragma unroll
    for (int i = 0; i < NI; ++i) s[i] = 0.f;
#pragma unroll 1   // one quartet of scalar weights live at a time
    for (int g4 = 0; g4 < 4; ++g4) {
        const float w0 = wp[g4*4+0], w1 = wp[g4*4+1],
                    w2 = wp[g4*4+2], w3 = wp[g4*4+3];
#pragma unroll
        for (int i = 0; i < NI; ++i) {
            const int n = wv + NWV*(I0 + i);
            if (n < NPG) {
                const double* hr = &h[n*HID + j*16 + g4*4];
                float t = s[i];
                t = fmaf((float)hr[0], w0, t);
                t = fmaf((float)hr[1], w1, t);
                t = fmaf((float)hr[2], w2, t);
                t = fmaf((float)hr[3], w3, t);
                s[i] = t;
            }
        }
    }
#pragma unroll
    for (int i = 0; i < NI; ++i) {
        const int n = wv + NWV*(I0 + i);
        if (n < NPG) {
            float v = s[i];
            v += __shfl_xor(v, 1, 64);
            v += __shfl_xor(v, 2, 64);
            if (j == 0) y1all[n*16 + ch] += v;   // unique (n,ch) owner
        }
    }
}

__device__ __forceinline__ void dot_accum(
    const double* __restrict__ h, const float* __restrict__ c1w,
    float* __restrict__ y1all, int lane, int wv, int l)
{
    const int ch = lane >> 2, j = lane & 3;
    const float* wp = &c1w[ch*LATD + l*HID + j*16];
    dot_part<0, 5>(h, wp, y1all, lane, wv, ch, j);
    __builtin_amdgcn_sched_barrier(0);
    dot_part<5, 4>(h, wp, y1all, lane, wv, ch, j);
}

// launch_bounds(768, 6): 6 waves/EU -> VGPR cap ~42 -> two 12-wave WGs/CU
// (confirmed: occupancy ~67%). Scheduling fences + smaller batches bring the
// transient peak under the cap. Spill tripwire: WRITE_SIZE >> 64KB.
__global__ void
__launch_bounds__(NTHR, 6)
seal_fused(const int* __restrict__ z,
                const int* __restrict__ esrc, const int* __restrict__ edst,
                const float* __restrict__ zemb,
                const float* __restrict__ W0, const float* __restrict__ b0,
                const float* __restrict__ W1, const float* __restrict__ b1,
                const float* __restrict__ W2, const float* __restrict__ b2,
                const float* __restrict__ W3, const float* __restrict__ b3,
                const float* __restrict__ c1w, const float* __restrict__ c1b,
                const float* __restrict__ c2w, const float* __restrict__ c2b,
                const float* __restrict__ l1w, const float* __restrict__ l1b,
                const float* __restrict__ l2w, const float* __restrict__ l2b,
                float* __restrict__ out)
{
    __shared__ __align__(16) char smem[SMEM_SZ];
    double* h64    = (double*)(smem + OFF_H64);
    unsigned short* adj = (unsigned short*)(smem + OFF_ADJ);
    float*  y1all  = (float*) (smem + OFF_Y1ALL);
    float*  dinv   = (float*) (smem + OFF_DINV);
    int*    zl     = (int*)   (smem + OFF_ZL);
    int*    cnt    = (int*)   (smem + OFF_CNT);
    double* s4     = (double*)(smem + OFF_S4);
    double* key64  = (double*)(smem + OFF_KEY64);
    int*    sel    = (int*)   (smem + OFF_SEL);
    float*  y1     = (float*) (smem + OFF_Y1);
    float*  y1p    = (float*) (smem + OFF_Y1P);
    float*  y2f    = (float*) (smem + OFF_Y2F);
    float*  part   = (float*) (smem + OFF_PART);
    float*  o128   = (float*) (smem + OFF_O128);

    const int g     = blockIdx.x;
    const int t     = threadIdx.x;
    const int lane  = t & 63;
    const int wv    = t >> 6;
    const int nbase = g * NPG;
    const int ebase = g * EPG;

    // ---- stage edges in registers (single global read; <=2 edges/thread) ---
    // EPG=800 > NTHR=768: threads 0..31 carry a second edge. Insertion order
    // differs from the 1024-thread version, but rows are insertion-sorted
    // before use -> final accumulation order (and sums) are unchanged.
    int e0s, e0d, e1s = 0, e1d = -1;
    e0s = esrc[ebase + t] - nbase;
    e0d = edst[ebase + t] - nbase;
    if (t < EPG - NTHR) {
        e1s = esrc[ebase + NTHR + t] - nbase;
        e1d = edst[ebase + NTHR + t] - nbase;
    }
    for (int i = t; i < NPG; i += NTHR) { zl[i] = z[nbase+i]; cnt[i] = 0; }
    __syncthreads();
    atomicAdd(&cnt[e0d], 1);
    if (e1d >= 0) atomicAdd(&cnt[e1d], 1);
    __syncthreads();
    for (int i = t; i < NPG; i += NTHR) {
        dinv[i] = (float)(1.0 / sqrt((double)(cnt[i] + 1)));
        cnt[i] = 0;
    }
    __syncthreads();
    // ---- adjacency fill: BYTE offsets u*512 into the f64 h array ----
    { const int p = atomicAdd(&cnt[e0d], 1); if (p < MAXD) adj[e0d*MAXD + p] = (unsigned short)(e0s << 9); }
    if (e1d >= 0) { const int p = atomicAdd(&cnt[e1d], 1); if (p < MAXD) adj[e1d*MAXD + p] = (unsigned short)(e1s << 9); }
    __syncthreads();
    // ---- pad + sort rows (deterministic accumulation) ; embedding gather ----
    if (t < NPG) {
        const int deg = min(cnt[t], MAXD);
        unsigned short* row = &adj[t*MAXD];
        for (int j = deg; j < MAXD; ++j) row[j] = (unsigned short)(NPG << 9);  // -> zero row
        for (int a = 1; a < deg; ++a) {
            const unsigned short x = row[a];
            int bp = a - 1;
            while (bp >= 0 && row[bp] > x) { row[bp+1] = row[bp]; --bp; }
            row[bp+1] = x;
        }
        row[0] |= (unsigned short)((deg + 7) >> 3);   // encode gq; cnt[] dies here
    }
    for (int i = t; i < (NPG+1)*HID; i += NTHR) {
        const int n = i >> 6, k = i & 63;
        h64[i] = (n < NPG) ? (double)zemb[zl[n]*HID + k] : 0.0;   // row 100 = 0
    }
    __syncthreads();
    // zl/cnt overlays now dead: reclaim as y1all zeros. Ordering vs first
    // dot_accum is guaranteed by gcnA's internal barriers.
    for (int i = t; i < NPG*16; i += NTHR) y1all[i] = 0.f;

    // ====== phase A (f64): layers 0..2 with fused conv1 dot accumulation =====
    gcnA(h64, dinv, adj, W0, b0, lane, wv);
    dot_accum(h64, c1w, y1all, lane, wv, 0);
    gcnA(h64, dinv, adj, W1, b1, lane, wv);
    dot_accum(h64, c1w, y1all, lane, wv, 1);
    gcnA(h64, dinv, adj, W2, b2, lane, wv);
    dot_accum(h64, c1w, y1all, lane, wv, 2);

    // ---- s4 = (h3 @ W3) * dinv (pre-scaled), f64, own rows ----
    // Lane-packed staging: after the full 64-lane reduce every lane holds the
    // row sum; keep row wv+12*i's value only in lane i -> ONE live VGPR pair.
    // The s4 LDS slot overlays h64, so the write waits for the barrier proving
    // all h64 reads are done.
    double s4pack = 0.0;
    {
        const double w3d = (double)W3[lane];
#pragma unroll
        for (int i = 0; i < ROWS; ++i) {
            const int n = wv + NWV*i;
            double v = (n < NPG) ? h64[n*HID + lane] * w3d : 0.0;
#pragma unroll
            for (int off = 32; off; off >>= 1) v += __shfl_xor(v, off, 64);
            s4pack = (lane == i) ? v : s4pack;
            __builtin_amdgcn_sched_barrier(0);   // one reduce chain at a time
        }
    }
    __syncthreads();            // h64 fully dead -> overlay region writable
    if (lane < ROWS) {
        const int n = wv + NWV*lane;
        if (n < NPG) s4[n] = s4pack * (double)dinv[n];
    }
    if (t == 0) s4[NPG] = 0.0;  // sentinel for key aggregation
    __syncthreads();
    // ---- layer-3 aggregate -> f64 sort keys (degree-adaptive) ----
    // Pairs joined as they load: <=5 live f64; summation tree identical:
    // ((z0+z1)+(z2+z3)) + ((z4+z5)+(z6+z7)).
    if (t < NPG) {
        const char* sb = (const char*)s4;
        const uint4* arow = (const uint4*)&adj[t*MAXD];
        const uint4 q0 = arow[0];
        const int gq = q0.x & 7;
        double acc;
        {
            double z01 = *(const double*)(sb + ((q0.x & 0xFE00) >> 6))
                       + *(const double*)(sb + ((q0.x >> 16)    >> 6));
            double z23 = *(const double*)(sb + ((q0.y & 0xFE00) >> 6))
                       + *(const double*)(sb + ((q0.y >> 16)    >> 6));
            const double t03 = z01 + z23;
            double z45 = *(const double*)(sb + ((q0.z & 0xFE00) >> 6))
                       + *(const double*)(sb + ((q0.z >> 16)    >> 6));
            double z67 = *(const double*)(sb + ((q0.w & 0xFE00) >> 6))
                       + *(const double*)(sb + ((q0.w >> 16)    >> 6));
            acc = t03 + (z45 + z67);
        }
#pragma unroll 1
        for (int q = 1; q < gq; ++q) {
            const uint4 qq = arow[q];
            double z01 = *(const double*)(sb + ((qq.x & 0xFE00) >> 6))
                       + *(const double*)(sb + ((qq.x >> 16)    >> 6));
            double z23 = *(const double*)(sb + ((qq.y & 0xFE00) >> 6))
                       + *(const double*)(sb + ((qq.y >> 16)    >> 6));
            const double t03 = z01 + z23;
            double z45 = *(const double*)(sb + ((qq.z & 0xFE00) >> 6))
                       + *(const double*)(sb + ((qq.z >> 16)    >> 6));
            double z67 = *(const double*)(sb + ((qq.w & 0xFE00) >> 6))
                       + *(const double*)(sb + ((qq.w >> 16)    >> 6));
            acc += t03 + (z45 + z67);
        }
        key64[t] = ftanh64(fma(acc + s4[t], (double)dinv[t], (double)b3[0]));
    }
    __syncthreads();
    // ---- stable top-K rank counting on f64 keys ----
    if (t < NPG) {
        const double kv = key64[t];
        int r = 0;
        for (int m = 0; m < NPG; ++m) {
            const double km = key64[m];
            r += (km > kv) || (km == kv && m < t);
        }
        if (r < KTOP) sel[r] = t;
    }
    __syncthreads();
    // ---- y1 assembly: partial dot + bias + key-channel term ----
    if (t < 16*KTOP) {
        const int ch = t & 15, r = t >> 4;
        const int n = sel[r];
        y1[ch*KTOP + r] = y1all[n*16 + ch] + c1b[ch]
                        + (float)key64[n] * c1w[ch*LATD + 192];
    }
    __syncthreads();
    // ---- maxpool(2,2) + fused relu ----
    if (t < 16*15) {
        const int ch = t & 15, p = t >> 4;
        y1p[ch*15 + p] = fmaxf(fmaxf(y1[ch*KTOP + 2*p], y1[ch*KTOP + 2*p + 1]), 0.f);
    }
    __syncthreads();
    // ---- conv2 [32][16][5], relu (weights from L2) ----
    if (t < 32*11) {
        const int o = t & 31, p = t >> 5;
        float acc = c2b[o];
        const float* wr = &c2w[o*80];
#pragma unroll
        for (int i = 0; i < 16; ++i)
#pragma unroll
            for (int kk = 0; kk < 5; ++kk)
                acc = fmaf(wr[i*5+kk], y1p[i*15 + p + kk], acc);
        y2f[o*11 + p] = fmaxf(acc, 0.f);
    }
    __syncthreads();
    // ---- lin1: 352 -> 128 (6-way f-split: 768 = 6x128 exactly), relu ----
    {
        const int j = t & 127, pid = t >> 7;      // pid 0..5
        const int f0 = pid * 59;
        const int f1 = (f0 + 59 < 352) ? f0 + 59 : 352;
        float acc = 0.f;
        for (int f = f0; f < f1; ++f) acc = fmaf(y2f[f], l1w[f*128 + j], acc);
        part[pid*128 + j] = acc;
    }
    __syncthreads();
    if (t < 128) {
        float acc = l1b[t];
#pragma unroll
        for (int pid = 0; pid < 6; ++pid) acc += part[pid*128 + t];
        o128[t] = fmaxf(acc, 0.f);
    }
    __syncthreads();
    // ---- lin2: 128 -> 1 ----
    if (t < 64) {
        float acc = fmaf(o128[t], l2w[t], o128[t+64]*l2w[t+64]);
#pragma unroll
        for (int off = 32; off; off >>= 1) acc += __shfl_xor(acc, off, 64);
        if (t == 0) out[g] = acc + l2b[0];
    }
}

extern "C" void kernel_launch(void* const* d_in, const int* in_sizes, int n_in,
                              void* d_out, int out_size, void* d_ws, size_t ws_size,
                              hipStream_t stream)
{
    const int*   z    = (const int*)d_in[0];
    const int*   ei   = (const int*)d_in[1];
    const float* zemb = (const float*)d_in[3];
    const float* W0   = (const float*)d_in[4];
    const float* b0   = (const float*)d_in[5];
    const float* W1   = (const float*)d_in[6];
    const float* b1   = (const float*)d_in[7];
    const float* W2   = (const float*)d_in[8];
    const float* b2   = (const float*)d_in[9];
    const float* W3   = (const float*)d_in[10];
    const float* b3   = (const float*)d_in[11];
    const float* c1w  = (const float*)d_in[12];
    const float* c1b  = (const float*)d_in[13];
    const float* c2w  = (const float*)d_in[14];
    const float* c2b  = (const float*)d_in[15];
    const float* l1w  = (const float*)d_in[16];
    const float* l1b  = (const float*)d_in[17];
    const float* l2w  = (const float*)d_in[18];
    const float* l2b  = (const float*)d_in[19];
    float*       out  = (float*)d_out;

    const int E = in_sizes[1] / 2;   // 1638400
    seal_fused<<<NGR, NTHR, 0, stream>>>(z, ei, ei + E, zemb,
                                         W0, b0, W1, b1, W2, b2, W3, b3,
                                         c1w, c1b, c2w, c2b, l1w, l1b, l2w, l2b,
                                         out);
}

// Round 10
// 444.537 us; speedup vs baseline: 1.1636x; 1.1636x over previous
//
#include <hip/hip_runtime.h>
#include <math.h>

#define NPG  100
#define NGR  2048
#define EPG  800
#define HID  64
#define LATD 193
#define KTOP 30
#define NTHR 768     // 12 waves/WG; 2 WGs/CU = 6 waves/SIMD (occupancy ~67%)
#define NWV  12
#define ROWS 9       // ceil(100/12)
#define MAXD 32

// ---------------- LDS layout (byte offsets), 77200 B ------------------------
// Residency: VGPR<=42 (launch_bounds(768,6), alloc 40) -> 2 WGs/CU. r9
// FALSIFIED the "scheduler-transient" spill model (fences changed nothing);
// the ~100 B/thread scratch spill is the agg[] tail held ACROSS the gather
// barrier (in-place h update: all gathers before any write). Fix: stage rows
// 7-8's raw sums in an explicit LDS buffer (aggl, 12.3 KB) -- LDS round-trip
// instead of HBM scratch. Budget: 2 x 77.2 KB = 154.4 KB <= 160 KB/CU (r0's
// "64KB limit" was a misdiagnosis -- that config was register-limited).
#define OFF_H64    0       // double[101][64] = 51712 (row 100 = zero sentinel)
#define OFF_ADJ    51712   // ushort[100*32] = 6400 -> 58112 (BYTE offsets u*512; bits0-2 of row[0] = group count)
#define OFF_Y1ALL  58112   // float[100*16] = 6400 -> 64512
#define OFF_DINV   64512   // float[100] = 400 -> 64912 (f64 rsqrt rounded once)
#define OFF_AGGL   64912   // double[2][768] = 12288 -> 77200 (agg rows 7-8 across barrier)
#define SMEM_SZ    77200
// pre-phase-A overlays inside y1all (dead after pad/sort; y1all zeroed later):
#define OFF_ZL     OFF_Y1ALL           // int[100]
#define OFF_CNT    (OFF_Y1ALL + 400)   // int[100]
// tail overlays inside dead h64 region:
#define OFF_Y1P    0       // 960
#define OFF_Y2F    960     // 960+1408 -> 2368
#define OFF_PART   2368    // 6*128*4 = 3072 -> 5440 (4096 reserved)
#define OFF_O128   6464    // 512 -> 6976
#define OFF_Y1     6976    // 16*30*4 = 1920 -> 8896
#define OFF_S4     8896    // double[101] = 808 -> 9704 (written AFTER h64 dead, lane-packed)
#define OFF_KEY64  9704    // double[100] = 800 -> 10504
#define OFF_SEL    10504   // int[32] = 128 -> 10632

// Branch-free f64 tanh (abs err ~1e-13). Divide replaced by float-seeded
// reciprocal + 2 Newton steps (rel err ~1e-28 -> <=1 ulp).
__device__ __forceinline__ double ftanh64(double x) {
    const double y  = fmin(fabs(x) * 2.0, 44.0);
    const double nf = rint(y * 1.4426950408889634074);
    double r = fma(-nf, 6.93147180369123816490e-01, y);
    r = fma(-nf, 1.90821492927058770002e-10, r);
    double p = 2.7557319223985888e-07;
    p = fma(p, r, 2.7557319223985893e-06);
    p = fma(p, r, 2.4801587301587302e-05);
    p = fma(p, r, 1.9841269841269841e-04);
    p = fma(p, r, 1.3888888888888889e-03);
    p = fma(p, r, 8.3333333333333332e-03);
    p = fma(p, r, 4.1666666666666664e-02);
    p = fma(p, r, 1.6666666666666666e-01);
    p = fma(p, r, 0.5);
    p = fma(p, r, 1.0);
    p = fma(p, r, 1.0);
    const double e = p * __longlong_as_double((long long)(1023 + (int)nf) << 52);
    const double d = e + 1.0;
    double rc = (double)(1.0f / (float)d);        // f32 seed (~1.2e-7 rel)
    rc = fma(fma(-d, rc, 1.0), rc, rc);           // Newton 1 -> ~1.4e-14
    rc = fma(fma(-d, rc, 1.0), rc, rc);           // Newton 2 -> exact-ish
    const double t = fma(-2.0, rc, 1.0);
    return copysign(t, x);
}

// Matmul row-batch: rows I0..I0+NI-1 of h@W, written back pre-scaled by dinv.
// QUARTET groups (16 x 4 W-columns) as 4 SCALAR floats (no register arrays
// under partial unroll -- rule #20; r8-proven). Summation tree = r8's.
template<int I0, int NI>
__device__ __forceinline__ void gcn_mm(
    double* __restrict__ h, const float* __restrict__ dinv,
    const float* __restrict__ W, int lane, int wv)
{
    double acc[NI];
#pragma unroll
    for (int i = 0; i < NI; ++i) acc[i] = 0.;

#pragma unroll 1   // one quartet of scalar weights live at a time
    for (int grp = 0; grp < 16; ++grp) {
        const float* wp = &W[(grp*4)*HID + lane];
        const float wfa = wp[0];
        const float wfb = wp[HID];
        const float wfc = wp[2*HID];
        const float wfd = wp[3*HID];
#pragma unroll
        for (int i = 0; i < NI; ++i) {
            const int n = wv + NWV*(I0 + i);
            if (n < NPG) {
                const double2* r2 = (const double2*)&h[n*HID + grp*4];
                const double2 x01 = r2[0], x23 = r2[1];
                const double a0 = x01.x * (double)wfa;
                const double a1 = x01.y * (double)wfb;
                const double a2 = x23.x * (double)wfc;
                const double a3 = x23.y * (double)wfd;
                acc[i] += (a0+a1)+(a2+a3);
            }
        }
    }
#pragma unroll
    for (int i = 0; i < NI; ++i) {
        const int n = wv + NWV*(I0 + i);
        if (n < NPG) h[n*HID + lane] = acc[i] * (double)dinv[n];   // pre-scaled
    }
}

// Raw adjacency-gather for row n: returns (a0+a1), the pairwise sum of the
// (pre-scaled) neighbor values. Self-term/dinv/bias are applied POST-barrier
// (same fma expression evaluated later -> bit-identical to r8).
__device__ __forceinline__ double raw_row(
    const char* __restrict__ hb, const unsigned short* __restrict__ adj, int n)
{
    const uint4* arow = (const uint4*)&adj[n*MAXD];
    const uint4 q0 = arow[0];
    const int gq = q0.x & 7;          // encoded group count (0..4)
    double a0, a1;
    a0  = *(const double*)(hb + (q0.x & 0xFE00));
    a1  = *(const double*)(hb + (q0.x >> 16));
    a0 += *(const double*)(hb + (q0.y & 0xFE00));
    a1 += *(const double*)(hb + (q0.y >> 16));
    a0 += *(const double*)(hb + (q0.z & 0xFE00));
    a1 += *(const double*)(hb + (q0.z >> 16));
    a0 += *(const double*)(hb + (q0.w & 0xFE00));
    a1 += *(const double*)(hb + (q0.w >> 16));
#pragma unroll 1   // serial q-loop (uint4 qq: vector reg, no array -> safe)
    for (int q = 1; q < gq; ++q) {
        const uint4 qq = arow[q];
        a0 += *(const double*)(hb + (qq.x & 0xFE00));
        a1 += *(const double*)(hb + (qq.x >> 16));
        a0 += *(const double*)(hb + (qq.y & 0xFE00));
        a1 += *(const double*)(hb + (qq.y >> 16));
        a0 += *(const double*)(hb + (qq.z & 0xFE00));
        a1 += *(const double*)(hb + (qq.z >> 16));
        a0 += *(const double*)(hb + (qq.w & 0xFE00));
        a1 += *(const double*)(hb + (qq.w >> 16));
    }
    return a0 + a1;
}

// f64 in-place GCN layer. Matmul: two row-batches (5+4, r8-proven). Gather:
// rows 0-6 (always valid: wv+72<=83) raw sums in 14 regs; rows 7-8 staged to
// the aggl LDS buffer (own slot; barrier orders write->read) -- this is the
// across-barrier state that was spilling to HBM scratch at the 42-reg cap.
// Post-barrier: fma(raw + self, dinv, bj) then tanh -- bit-identical math
// (self slot h[n][lane] is written only by its owner, later in this loop).
__device__ __forceinline__ void gcnA(
    double* __restrict__ h, const float* __restrict__ dinv,
    const unsigned short* __restrict__ adj, double* __restrict__ aggl,
    const float* __restrict__ W, const float* __restrict__ b,
    int lane, int wv, int t)
{
    gcn_mm<0, 5>(h, dinv, W, lane, wv);
    gcn_mm<5, 4>(h, dinv, W, lane, wv);
    __syncthreads();

    const char* hb = (const char*)h + lane*8;
    double agg[7];
#pragma unroll
    for (int i = 0; i < 7; ++i)
        agg[i] = raw_row(hb, adj, wv + NWV*i);      // n <= 83, always valid
    aggl[t] = raw_row(hb, adj, wv + NWV*7);         // n = 84..95, always valid
    {
        const int n8 = wv + NWV*8;                  // 96..107: valid for wv<4
        if (n8 < NPG) aggl[NTHR + t] = raw_row(hb, adj, n8);
    }
    __syncthreads();

    const double bj = (double)b[lane];
#pragma unroll
    for (int i = 0; i < ROWS; ++i) {
        const int n = wv + NWV*i;
        if (n < NPG) {
            const double raw = (i < 7) ? agg[i] : aggl[(i-7)*NTHR + t];
            h[n*HID + lane] = ftanh64(fma(raw + h[n*HID + lane],
                                          (double)dinv[n], bj));
        }
    }
    // no trailing barrier: post-agg ops touch only own rows until next matmul barrier
}

// conv1 partial dots for layer l, accumulated straight into LDS y1all.
// Quad-split: lane = ch*4+j. Quartet-outer with 4 SCALAR weights + persistent
// s[ROWS] (static indices -> registers). Per-row k-order 0..15 ascending ->
// f32 accumulation BIT-IDENTICAL (r8-proven version).
__device__ __forceinline__ void dot_accum(
    const double* __restrict__ h, const float* __restrict__ c1w,
    float* __restrict__ y1all, int lane, int wv, int l)
{
    const int ch = lane >> 2, j = lane & 3;
    const float* wp = &c1w[ch*LATD + l*HID + j*16];
    float s[ROWS];
#pragma unroll
    for (int i = 0; i < ROWS; ++i) s[i] = 0.f;
#pragma unroll 1   // one quartet of scalar weights live at a time
    for (int g4 = 0; g4 < 4; ++g4) {
        const float w0 = wp[g4*4+0], w1 = wp[g4*4+1],
                    w2 = wp[g4*4+2], w3 = wp[g4*4+3];
#pragma unroll
        for (int i = 0; i < ROWS; ++i) {
            const int n = wv + NWV*i;
            if (n < NPG) {
                const double* hr = &h[n*HID + j*16 + g4*4];
                float t = s[i];
                t = fmaf((float)hr[0], w0, t);
                t = fmaf((float)hr[1], w1, t);
                t = fmaf((float)hr[2], w2, t);
                t = fmaf((float)hr[3], w3, t);
                s[i] = t;
            }
        }
    }
#pragma unroll
    for (int i = 0; i < ROWS; ++i) {
        const int n = wv + NWV*i;
        if (n < NPG) {
            float v = s[i];
            v += __shfl_xor(v, 1, 64);
            v += __shfl_xor(v, 2, 64);
            if (j == 0) y1all[n*16 + ch] += v;   // unique (n,ch) owner
        }
    }
}

// launch_bounds(768, 6): 6 waves/EU -> VGPR cap ~42 -> two 12-wave WGs/CU.
// Spill tripwires: WRITE_SIZE >> 64KB (scratch), Occupancy < 60 (LDS model).
__global__ void
__launch_bounds__(NTHR, 6)
seal_fused(const int* __restrict__ z,
                const int* __restrict__ esrc, const int* __restrict__ edst,
                const float* __restrict__ zemb,
                const float* __restrict__ W0, const float* __restrict__ b0,
                const float* __restrict__ W1, const float* __restrict__ b1,
                const float* __restrict__ W2, const float* __restrict__ b2,
                const float* __restrict__ W3, const float* __restrict__ b3,
                const float* __restrict__ c1w, const float* __restrict__ c1b,
                const float* __restrict__ c2w, const float* __restrict__ c2b,
                const float* __restrict__ l1w, const float* __restrict__ l1b,
                const float* __restrict__ l2w, const float* __restrict__ l2b,
                float* __restrict__ out)
{
    __shared__ __align__(16) char smem[SMEM_SZ];
    double* h64    = (double*)(smem + OFF_H64);
    unsigned short* adj = (unsigned short*)(smem + OFF_ADJ);
    float*  y1all  = (float*) (smem + OFF_Y1ALL);
    float*  dinv   = (float*) (smem + OFF_DINV);
    double* aggl   = (double*)(smem + OFF_AGGL);
    int*    zl     = (int*)   (smem + OFF_ZL);
    int*    cnt    = (int*)   (smem + OFF_CNT);
    double* s4     = (double*)(smem + OFF_S4);
    double* key64  = (double*)(smem + OFF_KEY64);
    int*    sel    = (int*)   (smem + OFF_SEL);
    float*  y1     = (float*) (smem + OFF_Y1);
    float*  y1p    = (float*) (smem + OFF_Y1P);
    float*  y2f    = (float*) (smem + OFF_Y2F);
    float*  part   = (float*) (smem + OFF_PART);
    float*  o128   = (float*) (smem + OFF_O128);

    const int g     = blockIdx.x;
    const int t     = threadIdx.x;
    const int lane  = t & 63;
    const int wv    = t >> 6;
    const int nbase = g * NPG;
    const int ebase = g * EPG;

    // ---- stage edges in registers (single global read; <=2 edges/thread) ---
    // EPG=800 > NTHR=768: threads 0..31 carry a second edge. Insertion order
    // differs from the 1024-thread version, but rows are insertion-sorted
    // before use -> final accumulation order (and sums) are unchanged.
    int e0s, e0d, e1s = 0, e1d = -1;
    e0s = esrc[ebase + t] - nbase;
    e0d = edst[ebase + t] - nbase;
    if (t < EPG - NTHR) {
        e1s = esrc[ebase + NTHR + t] - nbase;
        e1d = edst[ebase + NTHR + t] - nbase;
    }
    for (int i = t; i < NPG; i += NTHR) { zl[i] = z[nbase+i]; cnt[i] = 0; }
    __syncthreads();
    atomicAdd(&cnt[e0d], 1);
    if (e1d >= 0) atomicAdd(&cnt[e1d], 1);
    __syncthreads();
    for (int i = t; i < NPG; i += NTHR) {
        dinv[i] = (float)(1.0 / sqrt((double)(cnt[i] + 1)));
        cnt[i] = 0;
    }
    __syncthreads();
    // ---- adjacency fill: BYTE offsets u*512 into the f64 h array ----
    { const int p = atomicAdd(&cnt[e0d], 1); if (p < MAXD) adj[e0d*MAXD + p] = (unsigned short)(e0s << 9); }
    if (e1d >= 0) { const int p = atomicAdd(&cnt[e1d], 1); if (p < MAXD) adj[e1d*MAXD + p] = (unsigned short)(e1s << 9); }
    __syncthreads();
    // ---- pad + sort rows (deterministic accumulation) ; embedding gather ----
    if (t < NPG) {
        const int deg = min(cnt[t], MAXD);
        unsigned short* row = &adj[t*MAXD];
        for (int j = deg; j < MAXD; ++j) row[j] = (unsigned short)(NPG << 9);  // -> zero row
        for (int a = 1; a < deg; ++a) {
            const unsigned short x = row[a];
            int bp = a - 1;
            while (bp >= 0 && row[bp] > x) { row[bp+1] = row[bp]; --bp; }
            row[bp+1] = x;
        }
        row[0] |= (unsigned short)((deg + 7) >> 3);   // encode gq; cnt[] dies here
    }
    for (int i = t; i < (NPG+1)*HID; i += NTHR) {
        const int n = i >> 6, k = i & 63;
        h64[i] = (n < NPG) ? (double)zemb[zl[n]*HID + k] : 0.0;   // row 100 = 0
    }
    __syncthreads();
    // zl/cnt overlays now dead: reclaim as y1all zeros. Ordering vs first
    // dot_accum is guaranteed by gcnA's internal barriers.
    for (int i = t; i < NPG*16; i += NTHR) y1all[i] = 0.f;

    // ====== phase A (f64): layers 0..2 with fused conv1 dot accumulation =====
    gcnA(h64, dinv, adj, aggl, W0, b0, lane, wv, t);
    dot_accum(h64, c1w, y1all, lane, wv, 0);
    gcnA(h64, dinv, adj, aggl, W1, b1, lane, wv, t);
    dot_accum(h64, c1w, y1all, lane, wv, 1);
    gcnA(h64, dinv, adj, aggl, W2, b2, lane, wv, t);
    dot_accum(h64, c1w, y1all, lane, wv, 2);

    // ---- s4 = (h3 @ W3) * dinv (pre-scaled), f64, own rows ----
    // Lane-packed staging: after the full 64-lane reduce every lane holds the
    // row sum; keep row wv+12*i's value only in lane i -> ONE live VGPR pair.
    // The s4 LDS slot overlays h64, so the write waits for the barrier proving
    // all h64 reads are done.
    double s4pack = 0.0;
    {
        const double w3d = (double)W3[lane];
#pragma unroll
        for (int i = 0; i < ROWS; ++i) {
            const int n = wv + NWV*i;
            double v = (n < NPG) ? h64[n*HID + lane] * w3d : 0.0;
#pragma unroll
            for (int off = 32; off; off >>= 1) v += __shfl_xor(v, off, 64);
            s4pack = (lane == i) ? v : s4pack;
        }
    }
    __syncthreads();            // h64 fully dead -> overlay region writable
    if (lane < ROWS) {
        const int n = wv + NWV*lane;
        if (n < NPG) s4[n] = s4pack * (double)dinv[n];
    }
    if (t == 0) s4[NPG] = 0.0;  // sentinel for key aggregation
    __syncthreads();
    // ---- layer-3 aggregate -> f64 sort keys (degree-adaptive) ----
    // Pairs joined as they load: <=5 live f64; summation tree identical:
    // ((z0+z1)+(z2+z3)) + ((z4+z5)+(z6+z7)).
    if (t < NPG) {
        const char* sb = (const char*)s4;
        const uint4* arow = (const uint4*)&adj[t*MAXD];
        const uint4 q0 = arow[0];
        const int gq = q0.x & 7;
        double acc;
        {
            double z01 = *(const double*)(sb + ((q0.x & 0xFE00) >> 6))
                       + *(const double*)(sb + ((q0.x >> 16)    >> 6));
            double z23 = *(const double*)(sb + ((q0.y & 0xFE00) >> 6))
                       + *(const double*)(sb + ((q0.y >> 16)    >> 6));
            const double t03 = z01 + z23;
            double z45 = *(const double*)(sb + ((q0.z & 0xFE00) >> 6))
                       + *(const double*)(sb + ((q0.z >> 16)    >> 6));
            double z67 = *(const double*)(sb + ((q0.w & 0xFE00) >> 6))
                       + *(const double*)(sb + ((q0.w >> 16)    >> 6));
            acc = t03 + (z45 + z67);
        }
#pragma unroll 1
        for (int q = 1; q < gq; ++q) {
            const uint4 qq = arow[q];
            double z01 = *(const double*)(sb + ((qq.x & 0xFE00) >> 6))
                       + *(const double*)(sb + ((qq.x >> 16)    >> 6));
            double z23 = *(const double*)(sb + ((qq.y & 0xFE00) >> 6))
                       + *(const double*)(sb + ((qq.y >> 16)    >> 6));
            const double t03 = z01 + z23;
            double z45 = *(const double*)(sb + ((qq.z & 0xFE00) >> 6))
                       + *(const double*)(sb + ((qq.z >> 16)    >> 6));
            double z67 = *(const double*)(sb + ((qq.w & 0xFE00) >> 6))
                       + *(const double*)(sb + ((qq.w >> 16)    >> 6));
            acc += t03 + (z45 + z67);
        }
        key64[t] = ftanh64(fma(acc + s4[t], (double)dinv[t], (double)b3[0]));
    }
    __syncthreads();
    // ---- stable top-K rank counting on f64 keys ----
    if (t < NPG) {
        const double kv = key64[t];
        int r = 0;
        for (int m = 0; m < NPG; ++m) {
            const double km = key64[m];
            r += (km > kv) || (km == kv && m < t);
        }
        if (r < KTOP) sel[r] = t;
    }
    __syncthreads();
    // ---- y1 assembly: partial dot + bias + key-channel term ----
    if (t < 16*KTOP) {
        const int ch = t & 15, r = t >> 4;
        const int n = sel[r];
        y1[ch*KTOP + r] = y1all[n*16 + ch] + c1b[ch]
                        + (float)key64[n] * c1w[ch*LATD + 192];
    }
    __syncthreads();
    // ---- maxpool(2,2) + fused relu ----
    if (t < 16*15) {
        const int ch = t & 15, p = t >> 4;
        y1p[ch*15 + p] = fmaxf(fmaxf(y1[ch*KTOP + 2*p], y1[ch*KTOP + 2*p + 1]), 0.f);
    }
    __syncthreads();
    // ---- conv2 [32][16][5], relu (weights from L2) ----
    if (t < 32*11) {
        const int o = t & 31, p = t >> 5;
        float acc = c2b[o];
        const float* wr = &c2w[o*80];
#pragma unroll
        for (int i = 0; i < 16; ++i)
#pragma unroll
            for (int kk = 0; kk < 5; ++kk)
                acc = fmaf(wr[i*5+kk], y1p[i*15 + p + kk], acc);
        y2f[o*11 + p] = fmaxf(acc, 0.f);
    }
    __syncthreads();
    // ---- lin1: 352 -> 128 (6-way f-split: 768 = 6x128 exactly), relu ----
    {
        const int j = t & 127, pid = t >> 7;      // pid 0..5
        const int f0 = pid * 59;
        const int f1 = (f0 + 59 < 352) ? f0 + 59 : 352;
        float acc = 0.f;
        for (int f = f0; f < f1; ++f) acc = fmaf(y2f[f], l1w[f*128 + j], acc);
        part[pid*128 + j] = acc;
    }
    __syncthreads();
    if (t < 128) {
        float acc = l1b[t];
#pragma unroll
        for (int pid = 0; pid < 6; ++pid) acc += part[pid*128 + t];
        o128[t] = fmaxf(acc, 0.f);
    }
    __syncthreads();
    // ---- lin2: 128 -> 1 ----
    if (t < 64) {
        float acc = fmaf(o128[t], l2w[t], o128[t+64]*l2w[t+64]);
#pragma unroll
        for (int off = 32; off; off >>= 1) acc += __shfl_xor(acc, off, 64);
        if (t == 0) out[g] = acc + l2b[0];
    }
}

extern "C" void kernel_launch(void* const* d_in, const int* in_sizes, int n_in,
                              void* d_out, int out_size, void* d_ws, size_t ws_size,
                              hipStream_t stream)
{
    const int*   z    = (const int*)d_in[0];
    const int*   ei   = (const int*)d_in[1];
    const float* zemb = (const float*)d_in[3];
    const float* W0   = (const float*)d_in[4];
    const float* b0   = (const float*)d_in[5];
    const float* W1   = (const float*)d_in[6];
    const float* b1   = (const float*)d_in[7];
    const float* W2   = (const float*)d_in[8];
    const float* b2   = (const float*)d_in[9];
    const float* W3   = (const float*)d_in[10];
    const float* b3   = (const float*)d_in[11];
    const float* c1w  = (const float*)d_in[12];
    const float* c1b  = (const float*)d_in[13];
    const float* c2w  = (const float*)d_in[14];
    const float* c2b  = (const float*)d_in[15];
    const float* l1w  = (const float*)d_in[16];
    const float* l1b  = (const float*)d_in[17];
    const float* l2w  = (const float*)d_in[18];
    const float* l2b  = (const float*)d_in[19];
    float*       out  = (float*)d_out;

    const int E = in_sizes[1] / 2;   // 1638400
    seal_fused<<<NGR, NTHR, 0, stream>>>(z, ei, ei + E, zemb,
                                         W0, b0, W1, b1, W2, b2, W3, b3,
                                         c1w, c1b, c2w, c2b, l1w, l1b, l2w, l2b,
                                         out);
}